// Round 10
// baseline (538.691 us; speedup 1.0000x reference)
//
#include <hip/hip_runtime.h>
#include <hip/hip_bf16.h>
#include <hip/hip_cooperative_groups.h>

namespace cg = cooperative_groups;

#define N_NODES 100000
#define N_EDGES 1250000
#define D_FEAT  64
#define SB_NODES 512
#define SB_SHIFT 9
#define NSB     196            // ceil(100000/512) super-buckets
#define CAP_SB  7040           // mean 6400, sd 80 -> +8 sigma
#define OVF_CAP 8192
#define EPB_I4  1024           // int4 edge-loads per build chunk (4096 edges)
#define N_I4    (N_EDGES / 4)  // 312500
#define NCHUNK  ((N_I4 + EPB_I4 - 1) / EPB_I4)      // 306
#define NTILE   (N_NODES * D_FEAT / 8 / 256)        // 3125 bf16 tiles
#define NQ      (N_NODES / 4)                       // 25000 gather quads

// LDS pool, aliased per phase.
// build:  words[4096] | scn[256] | scnEx[197] | gbase[196] | posb[196] | cnt[196]
// repart: cntr[512] | scnr[256] | posr[512]
#define SH_WORDS 0
#define SH_SCN   4096
#define SH_SCNEX 4352
#define SH_GBASE 4549
#define SH_POSB  4745
#define SH_CNT   4941
#define SH_TOTAL 5137

__global__ __launch_bounds__(256) void onehop_fused(
    const float* __restrict__ x, const int* __restrict__ src,
    const int* __restrict__ dst, ushort* __restrict__ xh,
    uint* __restrict__ pairs, uint* __restrict__ pairsS,
    uint* __restrict__ offs, uint* __restrict__ fill,
    uint* __restrict__ ovfCnt, int2* __restrict__ ovf,
    float* __restrict__ out)
{
    __shared__ uint SH[SH_TOTAL];
    cg::grid_group grid = cg::this_grid();
    const int tid = threadIdx.x;
    const int bid = blockIdx.x;
    const int G   = gridDim.x;

    // ---------------- Phase 0: x -> bf16 (RNE); block 0 zeroes fill/ovfCnt ----
    if (bid == 0) {
        for (int i = tid; i < NSB + 2; i += 256) fill[i] = 0u;
    }
    for (int tile = bid; tile < NTILE; tile += G) {
        int t = tile * 256 + tid;
        const float4* x4 = (const float4*)x;
        float4 a = x4[2 * t];
        float4 b = x4[2 * t + 1];
        float f[8] = {a.x, a.y, a.z, a.w, b.x, b.y, b.z, b.w};
        uint h[8];
#pragma unroll
        for (int i = 0; i < 8; ++i) {
            uint u = __float_as_uint(f[i]);
            u += 0x7FFFu + ((u >> 16) & 1u);
            h[i] = u >> 16;
        }
        uint4 o;
        o.x = h[0] | (h[1] << 16);
        o.y = h[2] | (h[3] << 16);
        o.z = h[4] | (h[5] << 16);
        o.w = h[6] | (h[7] << 16);
        ((uint4*)xh)[t] = o;
    }
    grid.sync();

    // ---------------- Phase 1: coarse partition into super-buckets ------------
    {
        uint* words = SH + SH_WORDS;
        uint* scn   = SH + SH_SCN;
        uint* scnEx = SH + SH_SCNEX;
        uint* gbase = SH + SH_GBASE;
        uint* posb  = SH + SH_POSB;
        uint* cnt   = SH + SH_CNT;
        const int4* src4 = (const int4*)src;
        const int4* dst4 = (const int4*)dst;

        for (int c = bid; c < NCHUNK; c += G) {
            for (int i = tid; i < NSB; i += 256) cnt[i] = 0u;
            __syncthreads();

            const int i40 = c * EPB_I4;
            // pass 1: count dst super-buckets
#pragma unroll
            for (int k = 0; k < 4; ++k) {
                int i4 = i40 + tid + k * 256;
                if (i4 < N_I4) {
                    int4 d4 = dst4[i4];
                    atomicAdd(&cnt[((uint)d4.x) >> SB_SHIFT], 1u);
                    atomicAdd(&cnt[((uint)d4.y) >> SB_SHIFT], 1u);
                    atomicAdd(&cnt[((uint)d4.z) >> SB_SHIFT], 1u);
                    atomicAdd(&cnt[((uint)d4.w) >> SB_SHIFT], 1u);
                }
            }
            __syncthreads();

            // scan 256-wide (NSB<=256)
            uint myc = (tid < NSB) ? cnt[tid] : 0u;
            scn[tid] = myc;
            __syncthreads();
            for (int off = 1; off < 256; off <<= 1) {
                uint v = (tid >= off) ? scn[tid - off] : 0u;
                __syncthreads();
                scn[tid] += v;
                __syncthreads();
            }
            if (tid < NSB) {
                uint e = scn[tid] - myc;
                scnEx[tid] = e;
                posb[tid]  = e;
                gbase[tid] = myc ? atomicAdd(&fill[tid], myc) : 0u;
            }
            if (tid == 255) scnEx[NSB] = scn[255];
            __syncthreads();

            // pass 2: place words sorted-by-SB into LDS
#pragma unroll
            for (int k = 0; k < 4; ++k) {
                int i4 = i40 + tid + k * 256;
                if (i4 < N_I4) {
                    int4 d4 = dst4[i4];
                    int4 s4 = src4[i4];
                    int dd[4] = {d4.x, d4.y, d4.z, d4.w};
                    int ss[4] = {s4.x, s4.y, s4.z, s4.w};
#pragma unroll
                    for (int j = 0; j < 4; ++j) {
                        uint du = (uint)dd[j];
                        uint b = du >> SB_SHIFT;
                        uint w = ((du & (SB_NODES - 1u)) << 17) | (uint)ss[j];
                        uint r = atomicAdd(&posb[b], 1u);
                        words[r] = w;
                    }
                }
            }
            __syncthreads();

            // copy out: consecutive lanes -> consecutive global addresses
            const int n = (int)scnEx[NSB];
            for (int i = tid; i < n; i += 256) {
                int lo = 0, hi = NSB - 1;
                while (lo < hi) {
                    int mid = (lo + hi + 1) >> 1;
                    if ((int)scnEx[mid] <= i) lo = mid; else hi = mid - 1;
                }
                uint w = words[i];
                uint g = gbase[lo] + (uint)(i - (int)scnEx[lo]);
                if (g < CAP_SB) {
                    pairs[(size_t)lo * CAP_SB + g] = w;
                } else {
                    uint o = atomicAdd(ovfCnt, 1u);
                    if (o < OVF_CAP)
                        ovf[o] = make_int2((int)(w & 0x1FFFFu),
                                           (int)(((uint)lo << SB_SHIFT) | (w >> 17)));
                }
            }
            __syncthreads();
        }
    }
    grid.sync();

    // ---------------- Phase 2: per-SB counting sort -> CSR (pairsS, offs) -----
    {
        uint* cntr = SH;          // 512
        uint* scnr = SH + 512;    // 256
        uint* posr = SH + 768;    // 512

        for (int sb = bid; sb < NSB; sb += G) {
            cntr[tid] = 0u;
            cntr[tid + 256] = 0u;
            __syncthreads();
            const int n = min((int)fill[sb], CAP_SB);
            const size_t base = (size_t)sb * CAP_SB;
            for (int i = tid; i < n; i += 256)
                atomicAdd(&cntr[pairs[base + i] >> 17], 1u);
            __syncthreads();

            uint c0 = cntr[2 * tid], c1 = cntr[2 * tid + 1];
            scnr[tid] = c0 + c1;
            __syncthreads();
            for (int off = 1; off < 256; off <<= 1) {
                uint v = (tid >= off) ? scnr[tid - off] : 0u;
                __syncthreads();
                scnr[tid] += v;
                __syncthreads();
            }
            uint e = scnr[tid] - (c0 + c1);
            posr[2 * tid]     = e;
            posr[2 * tid + 1] = e + c0;
            offs[sb * SB_NODES + 2 * tid]     = e | (c0 << 16);
            offs[sb * SB_NODES + 2 * tid + 1] = (e + c0) | (c1 << 16);
            __syncthreads();

            for (int i = tid; i < n; i += 256) {
                uint w = pairs[base + i];
                uint r = atomicAdd(&posr[w >> 17], 1u);
                pairsS[base + r] = w & 0x1FFFFu;
            }
            __syncthreads();
        }
    }
    grid.sync();

    // ---------------- Phase 3: gather (wave per node), inline ovf fixup -------
    {
        const int lane = tid & 63;
        const int wid  = tid >> 6;
        const int sub  = lane >> 3;    // 8 edges in flight per wave
        const int l8   = lane & 7;     // 16B chunk of the 128B bf16 row
        const uint4* __restrict__ xrow = (const uint4*)xh;

        for (int q = bid; q < NQ; q += G) {
            const int node = q * 4 + wid;
            const uint v    = offs[node];
            const int start = (node >> SB_SHIFT) * CAP_SB + (int)(v & 0xFFFFu);
            const int deg   = (int)(v >> 16);

            float f[8];
#pragma unroll
            for (int j = 0; j < 8; ++j) f[j] = 0.f;

            int i = sub;
            for (; i + 8 < deg; i += 16) {
                uint s0 = pairsS[start + i];
                uint s1 = pairsS[start + i + 8];
                uint4 v0 = xrow[(size_t)s0 * 8 + l8];
                uint4 v1 = xrow[(size_t)s1 * 8 + l8];
                f[0] += __uint_as_float((v0.x & 0xFFFFu) << 16);
                f[1] += __uint_as_float(v0.x & 0xFFFF0000u);
                f[2] += __uint_as_float((v0.y & 0xFFFFu) << 16);
                f[3] += __uint_as_float(v0.y & 0xFFFF0000u);
                f[4] += __uint_as_float((v0.z & 0xFFFFu) << 16);
                f[5] += __uint_as_float(v0.z & 0xFFFF0000u);
                f[6] += __uint_as_float((v0.w & 0xFFFFu) << 16);
                f[7] += __uint_as_float(v0.w & 0xFFFF0000u);
                f[0] += __uint_as_float((v1.x & 0xFFFFu) << 16);
                f[1] += __uint_as_float(v1.x & 0xFFFF0000u);
                f[2] += __uint_as_float((v1.y & 0xFFFFu) << 16);
                f[3] += __uint_as_float(v1.y & 0xFFFF0000u);
                f[4] += __uint_as_float((v1.z & 0xFFFFu) << 16);
                f[5] += __uint_as_float(v1.z & 0xFFFF0000u);
                f[6] += __uint_as_float((v1.w & 0xFFFFu) << 16);
                f[7] += __uint_as_float(v1.w & 0xFFFF0000u);
            }
            if (i < deg) {
                uint s0 = pairsS[start + i];
                uint4 v0 = xrow[(size_t)s0 * 8 + l8];
                f[0] += __uint_as_float((v0.x & 0xFFFFu) << 16);
                f[1] += __uint_as_float(v0.x & 0xFFFF0000u);
                f[2] += __uint_as_float((v0.y & 0xFFFFu) << 16);
                f[3] += __uint_as_float(v0.y & 0xFFFF0000u);
                f[4] += __uint_as_float((v0.z & 0xFFFFu) << 16);
                f[5] += __uint_as_float(v0.z & 0xFFFF0000u);
                f[6] += __uint_as_float((v0.w & 0xFFFFu) << 16);
                f[7] += __uint_as_float(v0.w & 0xFFFF0000u);
            }

#pragma unroll
            for (int j = 0; j < 8; ++j) {
                f[j] += __shfl_xor(f[j], 8, 64);
                f[j] += __shfl_xor(f[j], 16, 64);
                f[j] += __shfl_xor(f[j], 32, 64);
            }

            const int nov = min((int)*ovfCnt, OVF_CAP);
            for (int e = 0; e < nov; ++e) {
                int2 p = ovf[e];
                if (p.y == node) {
                    float4 a = ((const float4*)x)[(size_t)p.x * 16 + l8 * 2];
                    float4 b = ((const float4*)x)[(size_t)p.x * 16 + l8 * 2 + 1];
                    f[0] += a.x; f[1] += a.y; f[2] += a.z; f[3] += a.w;
                    f[4] += b.x; f[5] += b.y; f[6] += b.z; f[7] += b.w;
                }
            }

            if (lane < 8) {
                float4* out4 = (float4*)out;
                out4[(size_t)node * 16 + l8 * 2]     = make_float4(f[0], f[1], f[2], f[3]);
                out4[(size_t)node * 16 + l8 * 2 + 1] = make_float4(f[4], f[5], f[6], f[7]);
            }
        }
    }
}

extern "C" void kernel_launch(void* const* d_in, const int* in_sizes, int n_in,
                              void* d_out, int out_size, void* d_ws, size_t ws_size,
                              hipStream_t stream) {
    const float* x = (const float*)d_in[0];
    const int* edge_index = (const int*)d_in[1];    // [2, N_EDGES] flat int32
    const int* src = edge_index;
    const int* dst = edge_index + N_EDGES;
    float* out = (float*)d_out;

    // ws: xh[12.8MB] | pairs[NSB*CAP_SB] | pairsS[NSB*CAP_SB] | offs[NSB*512] | fill[NSB] | ovfCnt+pad | ovf
    ushort* xh     = (ushort*)d_ws;
    uint*   pairs  = (uint*)(xh + (size_t)N_NODES * D_FEAT);
    uint*   pairsS = pairs + (size_t)NSB * CAP_SB;
    uint*   offs   = pairsS + (size_t)NSB * CAP_SB;
    uint*   fill   = offs + NSB * SB_NODES;
    uint*   ovfCnt = fill + NSB;
    int2*   ovf    = (int2*)(fill + NSB + 2);

    int perCU = 0;
    if (hipOccupancyMaxActiveBlocksPerMultiprocessor(&perCU, onehop_fused, 256, 0)
            != hipSuccess || perCU < 1)
        perCU = 4;
    int G = perCU * 256;          // 256 CUs on MI355X
    if (G > 2048) G = 2048;

    void* args[] = {(void*)&x, (void*)&src, (void*)&dst, (void*)&xh,
                    (void*)&pairs, (void*)&pairsS, (void*)&offs, (void*)&fill,
                    (void*)&ovfCnt, (void*)&ovf, (void*)&out};
    hipLaunchCooperativeKernel((const void*)onehop_fused, dim3(G), dim3(256),
                               args, 0, stream);
}